// Round 2
// baseline (906.084 us; speedup 1.0000x reference)
//
#include <hip/hip_runtime.h>
#include <math.h>

#define KS 48
#define TLEN 512
#define BN 1024
#define START_S 46
#define STOP_S 47
#define NEGV -10000.0f

__device__ __forceinline__ float bcast_lane0(float v) {
    return __builtin_bit_cast(float, __builtin_amdgcn_readfirstlane(__builtin_bit_cast(int, v)));
}

// grid = 2048: block b < 1024 -> forward (logZ + gold -> nll) for seq b
//              block b >= 1024 -> viterbi (path_score + path) for seq b-1024
__global__ __launch_bounds__(64) void crf_kernel(
    const float* __restrict__ feats,   // [B, T, K]
    const float* __restrict__ trans,   // [K, K]  trans[next, prev]
    const int*   __restrict__ tags,    // [B, T]
    float*       __restrict__ out)     // [B] nll | [B] path_score | [B*T] paths
{
    const int lane = threadIdx.x;
    const bool act = lane < KS;

    __shared__ float4 buf4[2][16];               // u-row (fwd) or w-row (vit), dbuf
    __shared__ unsigned char bp_sh[TLEN][KS];    // backpointers (vit only)
    __shared__ unsigned char path_sh[TLEN];
    float* buf = (float*)buf4;

    if (blockIdx.x < BN) {
        // ================= FORWARD =================
        const int b = blockIdx.x;
        const float* fb = feats + (size_t)b * TLEN * KS;
        const int*   tb = tags + (size_t)b * TLEN;

        float Erow[KS];   // exp(masked trans[next=lane][p]); exp(-10000)==0 masks for free
        {
            const float* tr = trans + (act ? lane : 0) * KS;
            #pragma unroll
            for (int p = 0; p < KS; ++p) {
                float tv = act ? tr[p] : NEGV;
                if (lane == START_S) tv = NEGV;
                if (p == STOP_S)     tv = NEGV;
                Erow[p] = __expf(tv);
            }
        }
        float tstart = act ? trans[lane * KS + START_S] : NEGV;
        if (lane == START_S) tstart = NEGV;

        // t = 0 peeled: only prev=START contributes (others exp(-1e4)=0 exactly);
        // matches reference bit-for-bit including alpha[START] = emit - 1e4.
        float emit  = act ? fb[lane] : -INFINITY;
        float alpha = emit + tstart;

        for (int t = 1; t < TLEN; ++t) {
            float emit_n = act ? fb[t * KS + lane] : -INFINITY;  // prefetch
            // lane-0 alpha is always finite and within ~e^15 of every finite
            // lane -> valid LSE shift; replaces the 6-shuffle max reduce.
            float s  = bcast_lane0(alpha);
            float ue = __expf(alpha - s);            // -inf lanes -> 0
            const int bsel = t & 1;
            buf[bsel * 64 + lane] = ue;
            __syncthreads();                         // 1-wave block: compiles to waitcnt
            const float4* uu = (const float4*)(buf + bsel * 64);
            float a0 = 0.f, a1 = 0.f, a2 = 0.f, a3 = 0.f;
            #pragma unroll
            for (int g = 0; g < KS / 4; ++g) {       // 12 ds_read_b128, 4 acc chains
                float4 u = uu[g];
                a0 = fmaf(u.x, Erow[4 * g + 0], a0);
                a1 = fmaf(u.y, Erow[4 * g + 1], a1);
                a2 = fmaf(u.z, Erow[4 * g + 2], a2);
                a3 = fmaf(u.w, Erow[4 * g + 3], a3);
            }
            alpha = emit_n + s + __logf((a0 + a1) + (a2 + a3));  // acc==0 -> -inf (START), benign
        }

        float tstop = act ? trans[STOP_S * KS + lane] : NEGV;
        if (lane == STOP_S) tstop = NEGV;
        float z = alpha + tstop;
        float mz = z;
        #pragma unroll
        for (int off = 32; off; off >>= 1)
            mz = fmaxf(mz, __shfl_xor(mz, off, 64));
        float se = __expf(z - mz);
        #pragma unroll
        for (int off = 32; off; off >>= 1)
            se += __shfl_xor(se, off, 64);
        float logZ = mz + __logf(se);

        // gold score: 64 lanes, 8 timesteps each
        float g = 0.0f;
        for (int t = lane; t < TLEN; t += 64) {
            int tg = tb[t];
            int pg = (t == 0) ? START_S : tb[t - 1];
            g += fb[t * KS + tg] + trans[tg * KS + pg];
        }
        #pragma unroll
        for (int off = 32; off; off >>= 1)
            g += __shfl_xor(g, off, 64);
        g += trans[STOP_S * KS + tb[TLEN - 1]];

        if (lane == 0) out[b] = logZ - g;
    } else {
        // ================= VITERBI =================
        const int b = blockIdx.x - BN;
        const float* fb = feats + (size_t)b * TLEN * KS;

        float Trow[KS];   // masked trans[next=lane][p] — same single add as reference
        {
            const float* tr = trans + (act ? lane : 0) * KS;
            #pragma unroll
            for (int p = 0; p < KS; ++p) {
                float tv = act ? tr[p] : NEGV;
                if (lane == START_S) tv = NEGV;
                if (p == STOP_S)     tv = NEGV;
                Trow[p] = tv;
            }
        }

        float vit  = (lane == START_S) ? 0.0f : NEGV;
        float emit = act ? fb[lane] : 0.0f;

        for (int t = 0; t < TLEN; ++t) {
            int tn = (t + 1 < TLEN) ? t + 1 : t;
            float emit_n = act ? fb[tn * KS + lane] : 0.0f;   // prefetch
            const int bsel = t & 1;
            buf[bsel * 64 + lane] = vit;
            __syncthreads();
            const float4* ww = (const float4*)(buf + bsel * 64);

            // tree argmax: exact max (fp max associative), unique w.p. 1 so
            // tie-break order is immaterial; scores use the reference's exact add.
            float bs[12]; int ib[12];
            #pragma unroll
            for (int g = 0; g < KS / 4; ++g) {
                float4 w = ww[g];
                float s0 = w.x + Trow[4 * g + 0];
                float s1 = w.y + Trow[4 * g + 1];
                float s2 = w.z + Trow[4 * g + 2];
                float s3 = w.w + Trow[4 * g + 3];
                float m01 = fmaxf(s0, s1); int i01 = (s1 > s0) ? 4 * g + 1 : 4 * g + 0;
                float m23 = fmaxf(s2, s3); int i23 = (s3 > s2) ? 4 * g + 3 : 4 * g + 2;
                bs[g] = fmaxf(m01, m23);   ib[g]  = (m23 > m01) ? i23 : i01;
            }
            #pragma unroll
            for (int st = 0; st < 6; ++st) {   // 12 -> 6
                float a = bs[2 * st], c = bs[2 * st + 1];
                int ia = ib[2 * st], ic = ib[2 * st + 1];
                bs[st] = fmaxf(a, c); ib[st] = (c > a) ? ic : ia;
            }
            #pragma unroll
            for (int st = 0; st < 3; ++st) {   // 6 -> 3
                float a = bs[2 * st], c = bs[2 * st + 1];
                int ia = ib[2 * st], ic = ib[2 * st + 1];
                bs[st] = fmaxf(a, c); ib[st] = (c > a) ? ic : ia;
            }
            float best = fmaxf(bs[0], bs[1]);
            int   bi   = (bs[1] > bs[0]) ? ib[1] : ib[0];
            bi   = (bs[2] > best) ? ib[2] : bi;
            best = fmaxf(best, bs[2]);

            if (act) bp_sh[t][lane] = (unsigned char)bi;
            vit  = best + emit;
            emit = emit_n;
        }

        float tstop = act ? trans[STOP_S * KS + lane] : NEGV;
        if (lane == STOP_S) tstop = NEGV;
        float term = act ? (vit + tstop) : -3.0e38f;
        float bv = term;
        int   bidx = act ? lane : 9999;
        #pragma unroll
        for (int off = 32; off; off >>= 1) {
            float ov = __shfl_xor(bv, off, 64);
            int   oi = __shfl_xor(bidx, off, 64);
            if (ov > bv || (ov == bv && oi < bidx)) { bv = ov; bidx = oi; }
        }
        if (lane == 0) out[BN + b] = bv;

        // serial backtrace (uniform; broadcast LDS reads)
        int tag = bidx;
        for (int t = TLEN - 1; t >= 0; --t) {
            path_sh[t] = (unsigned char)tag;   // all lanes, same value
            tag = bp_sh[t][tag];
        }
        __syncthreads();
        float* pout = out + 2 * BN + (size_t)b * TLEN;
        for (int t = lane; t < TLEN; t += 64)
            pout[t] = (float)path_sh[t];
    }
}

extern "C" void kernel_launch(void* const* d_in, const int* in_sizes, int n_in,
                              void* d_out, int out_size, void* d_ws, size_t ws_size,
                              hipStream_t stream) {
    const float* feats = (const float*)d_in[0];
    const float* trans = (const float*)d_in[1];
    const int*   tags  = (const int*)d_in[2];
    float*       out   = (float*)d_out;
    (void)in_sizes; (void)n_in; (void)out_size; (void)d_ws; (void)ws_size;
    crf_kernel<<<dim3(2 * BN), dim3(64), 0, stream>>>(feats, trans, tags, out);
}

// Round 3
// 628.248 us; speedup vs baseline: 1.4422x; 1.4422x over previous
//
#include <hip/hip_runtime.h>
#include <math.h>

#define KS 48
#define TLEN 512
#define BN 1024
#define START_S 46
#define STOP_S 47
#define NEGV -10000.0f

typedef float v2f __attribute__((ext_vector_type(2)));

__device__ __forceinline__ float bcast_lane0(float v) {
    return __builtin_bit_cast(float, __builtin_amdgcn_readfirstlane(__builtin_bit_cast(int, v)));
}

// ============ main kernel: grid 2048, bp in global scratch ============
// block b < 1024   -> forward (logZ + gold -> nll) for seq b
// block b >= 1024  -> viterbi (path_score + path) for seq b-1024
// (1024 % 8 == 0, so seq i's fwd and vit blocks land on the same XCD)
__global__ __launch_bounds__(64) void crf_split(
    const float* __restrict__ feats,   // [B, T, K]
    const float* __restrict__ trans,   // [K, K]  trans[next, prev]
    const int*   __restrict__ tags,    // [B, T]
    float*       __restrict__ out,     // [B] nll | [B] path_score | [B*T] paths
    unsigned char* __restrict__ bp_g)  // [B, T, K] backpointers
{
    const int lane = threadIdx.x;
    const bool act = lane < KS;

    __shared__ float buf[2][64];                 // tiny: keeps occupancy VGPR-limited
    __shared__ unsigned char path_sh[TLEN];

    if (blockIdx.x < BN) {
        // ================= FORWARD =================
        const int b = blockIdx.x;
        const float* fb = feats + (size_t)b * TLEN * KS;
        const int*   tb = tags + (size_t)b * TLEN;

        float Erow[KS];   // exp(masked trans[next=lane][p]); exp(-10000)==0 masks for free
        {
            const float* tr = trans + (act ? lane : 0) * KS;
            #pragma unroll
            for (int p = 0; p < KS; ++p) {
                float tv = act ? tr[p] : NEGV;
                if (lane == START_S) tv = NEGV;
                if (p == STOP_S)     tv = NEGV;
                Erow[p] = __expf(tv);
            }
        }
        float tstart = act ? trans[lane * KS + START_S] : NEGV;
        if (lane == START_S) tstart = NEGV;

        // t=0 peeled: only prev=START contributes (others exp(-1e4)==0 exactly)
        float emit  = act ? fb[lane] : -INFINITY;
        float alpha = emit + tstart;

        for (int t = 1; t < TLEN; ++t) {
            float emit_n = act ? fb[t * KS + lane] : -INFINITY;
            // lane-0 alpha is always finite & within ~e^15 of all finite lanes
            float s  = bcast_lane0(alpha);
            float ue = __expf(alpha - s);            // -inf lanes -> 0
            const int bsel = t & 1;
            buf[bsel][lane] = ue;
            __syncthreads();                         // 1-wave block: waitcnt only
            const float4* uu = (const float4*)buf[bsel];
            v2f acc0 = {0.f, 0.f}, acc1 = {0.f, 0.f};
            #pragma unroll
            for (int g = 0; g < KS / 4; ++g) {       // 12 ds_read_b128 + 24 v_pk_fma_f32
                float4 u = uu[g];
                v2f ua = {u.x, u.y}, ub = {u.z, u.w};
                v2f ea = {Erow[4 * g + 0], Erow[4 * g + 1]};
                v2f eb = {Erow[4 * g + 2], Erow[4 * g + 3]};
                acc0 = __builtin_elementwise_fma(ua, ea, acc0);
                acc1 = __builtin_elementwise_fma(ub, eb, acc1);
            }
            // same reduction tree as round 2 (bit-identical, validated absmax 0)
            alpha = emit_n + s + __logf((acc0.x + acc0.y) + (acc1.x + acc1.y));
        }

        float tstop = act ? trans[STOP_S * KS + lane] : NEGV;
        if (lane == STOP_S) tstop = NEGV;
        float z = alpha + tstop;
        float mz = z;
        #pragma unroll
        for (int off = 32; off; off >>= 1)
            mz = fmaxf(mz, __shfl_xor(mz, off, 64));
        float se = __expf(z - mz);
        #pragma unroll
        for (int off = 32; off; off >>= 1)
            se += __shfl_xor(se, off, 64);
        float logZ = mz + __logf(se);

        float g = 0.0f;
        for (int t = lane; t < TLEN; t += 64) {
            int tg = tb[t];
            int pg = (t == 0) ? START_S : tb[t - 1];
            g += fb[t * KS + tg] + trans[tg * KS + pg];
        }
        #pragma unroll
        for (int off = 32; off; off >>= 1)
            g += __shfl_xor(g, off, 64);
        g += trans[STOP_S * KS + tb[TLEN - 1]];

        if (lane == 0) out[b] = logZ - g;
    } else {
        // ================= VITERBI =================
        const int b = blockIdx.x - BN;
        const float* fb = feats + (size_t)b * TLEN * KS;
        unsigned char* bpb = bp_g + (size_t)b * TLEN * KS;

        float Trow[KS];   // masked trans[next=lane][p] — reference's exact add
        {
            const float* tr = trans + (act ? lane : 0) * KS;
            #pragma unroll
            for (int p = 0; p < KS; ++p) {
                float tv = act ? tr[p] : NEGV;
                if (lane == START_S) tv = NEGV;
                if (p == STOP_S)     tv = NEGV;
                Trow[p] = tv;
            }
        }

        float vit  = (lane == START_S) ? 0.0f : NEGV;
        float emit = act ? fb[lane] : 0.0f;

        for (int t = 0; t < TLEN; ++t) {
            int tn = (t + 1 < TLEN) ? t + 1 : t;
            float emit_n = act ? fb[tn * KS + lane] : 0.0f;
            const int bsel = t & 1;
            buf[bsel][lane] = vit;
            __syncthreads();
            const float4* ww = (const float4*)buf[bsel];

            // tree argmax (validated bit-exact in round 2); v_pk_add_f32 for scores
            float bs[12]; int ib[12];
            #pragma unroll
            for (int g = 0; g < KS / 4; ++g) {
                float4 w = ww[g];
                v2f wa = {w.x, w.y}, wb = {w.z, w.w};
                v2f ta = {Trow[4 * g + 0], Trow[4 * g + 1]};
                v2f tc = {Trow[4 * g + 2], Trow[4 * g + 3]};
                v2f sa = wa + ta;                    // v_pk_add_f32
                v2f sb = wb + tc;
                float m01 = fmaxf(sa.x, sa.y); int i01 = (sa.y > sa.x) ? 4 * g + 1 : 4 * g + 0;
                float m23 = fmaxf(sb.x, sb.y); int i23 = (sb.y > sb.x) ? 4 * g + 3 : 4 * g + 2;
                bs[g] = fmaxf(m01, m23);       ib[g] = (m23 > m01) ? i23 : i01;
            }
            #pragma unroll
            for (int st = 0; st < 6; ++st) {
                float a = bs[2 * st], c = bs[2 * st + 1];
                int ia = ib[2 * st], ic = ib[2 * st + 1];
                bs[st] = fmaxf(a, c); ib[st] = (c > a) ? ic : ia;
            }
            #pragma unroll
            for (int st = 0; st < 3; ++st) {
                float a = bs[2 * st], c = bs[2 * st + 1];
                int ia = ib[2 * st], ic = ib[2 * st + 1];
                bs[st] = fmaxf(a, c); ib[st] = (c > a) ? ic : ia;
            }
            float best = fmaxf(bs[0], bs[1]);
            int   bi   = (bs[1] > bs[0]) ? ib[1] : ib[0];
            bi   = (bs[2] > best) ? ib[2] : bi;
            best = fmaxf(best, bs[2]);

            if (act) bpb[t * KS + lane] = (unsigned char)bi;   // fire-and-forget
            vit  = best + emit;
            emit = emit_n;
        }

        float tstop = act ? trans[STOP_S * KS + lane] : NEGV;
        if (lane == STOP_S) tstop = NEGV;
        float term = act ? (vit + tstop) : -3.0e38f;
        float bv = term;
        int   bidx = act ? lane : 9999;
        #pragma unroll
        for (int off = 32; off; off >>= 1) {
            float ov = __shfl_xor(bv, off, 64);
            int   oi = __shfl_xor(bidx, off, 64);
            if (ov > bv || (ov == bv && oi < bidx)) { bv = ov; bidx = oi; }
        }
        if (lane == 0) out[BN + b] = bv;

        // backtrace: uniform serial walk over own just-written bp (L2-resident)
        int tag = bidx;
        for (int t = TLEN - 1; t >= 0; --t) {
            if (lane == 0) path_sh[t] = (unsigned char)tag;
            tag = bpb[t * KS + tag];
        }
        __syncthreads();
        float* pout = out + 2 * BN + (size_t)b * TLEN;
        for (int t = lane; t < TLEN; t += 64)
            pout[t] = (float)path_sh[t];
    }
}

// ============ fallback (ws too small): round-1 fused kernel, proven ============
__global__ __launch_bounds__(64) void crf_fused(
    const float* __restrict__ feats, const float* __restrict__ trans,
    const int* __restrict__ tags, float* __restrict__ out)
{
    const int b    = blockIdx.x;
    const int lane = threadIdx.x;
    const bool act = lane < KS;

    __shared__ float4 u4[KS / 4];
    __shared__ float4 w4[KS / 4];
    __shared__ unsigned char bp_sh[TLEN][KS];
    __shared__ unsigned char path_sh[TLEN];
    float* u_sh = (float*)u4;
    float* w_sh = (float*)w4;

    const float* fb = feats + (size_t)b * TLEN * KS;
    const int*   tb = tags + (size_t)b * TLEN;

    float Trow[KS], Erow[KS];
    {
        const float* tr = trans + (act ? lane : 0) * KS;
        #pragma unroll
        for (int p = 0; p < KS; ++p) {
            float tv = act ? tr[p] : NEGV;
            if (lane == START_S) tv = NEGV;
            if (p == STOP_S)     tv = NEGV;
            Trow[p] = tv;
            Erow[p] = __expf(tv);
        }
    }

    float alpha = (act && lane == START_S) ? 0.0f : -INFINITY;
    float vit   = (lane == START_S) ? 0.0f : (act ? NEGV : -3.0e38f);

    for (int t = 0; t < TLEN; ++t) {
        float emit = act ? fb[t * KS + lane] : 0.0f;
        float m = alpha;
        #pragma unroll
        for (int off = 32; off; off >>= 1)
            m = fmaxf(m, __shfl_xor(m, off, 64));
        float ue = __expf(alpha - m);
        if (act) { u_sh[lane] = ue; w_sh[lane] = vit; }
        __syncthreads();
        float acc = 0.0f, best = -3.0e38f; int bp = 0;
        #pragma unroll
        for (int p = 0; p < KS; p += 4) {
            float4 uu = u4[p / 4];
            float4 vv = w4[p / 4];
            acc = fmaf(uu.x, Erow[p + 0], acc);
            acc = fmaf(uu.y, Erow[p + 1], acc);
            acc = fmaf(uu.z, Erow[p + 2], acc);
            acc = fmaf(uu.w, Erow[p + 3], acc);
            float s0 = vv.x + Trow[p + 0]; if (s0 > best) { best = s0; bp = p + 0; }
            float s1 = vv.y + Trow[p + 1]; if (s1 > best) { best = s1; bp = p + 1; }
            float s2 = vv.z + Trow[p + 2]; if (s2 > best) { best = s2; bp = p + 2; }
            float s3 = vv.w + Trow[p + 3]; if (s3 > best) { best = s3; bp = p + 3; }
        }
        __syncthreads();
        alpha = emit + m + __logf(acc);
        vit   = best + emit;
        if (act) bp_sh[t][lane] = (unsigned char)bp;
    }

    float tstop = act ? trans[STOP_S * KS + lane] : NEGV;
    if (lane == STOP_S) tstop = NEGV;
    float z = alpha + tstop;
    float mz = z;
    #pragma unroll
    for (int off = 32; off; off >>= 1)
        mz = fmaxf(mz, __shfl_xor(mz, off, 64));
    float se = __expf(z - mz);
    #pragma unroll
    for (int off = 32; off; off >>= 1)
        se += __shfl_xor(se, off, 64);
    float logZ = mz + __logf(se);

    float term = act ? (vit + tstop) : -3.0e38f;
    float bv = term;
    int   bi = act ? lane : 9999;
    #pragma unroll
    for (int off = 32; off; off >>= 1) {
        float ov = __shfl_xor(bv, off, 64);
        int   oi = __shfl_xor(bi, off, 64);
        if (ov > bv || (ov == bv && oi < bi)) { bv = ov; bi = oi; }
    }

    float g = 0.0f;
    for (int t = lane; t < TLEN; t += 64) {
        int tg = tb[t];
        int pg = (t == 0) ? START_S : tb[t - 1];
        g += fb[t * KS + tg] + trans[tg * KS + pg];
    }
    #pragma unroll
    for (int off = 32; off; off >>= 1)
        g += __shfl_xor(g, off, 64);
    g += trans[STOP_S * KS + tb[TLEN - 1]];

    if (lane == 0) { out[b] = logZ - g; out[BN + b] = bv; }

    int tag = bi;
    for (int t = TLEN - 1; t >= 0; --t) {
        if (lane == 0) path_sh[t] = (unsigned char)tag;
        tag = bp_sh[t][tag];
    }
    __syncthreads();
    float* pout = out + 2 * BN + (size_t)b * TLEN;
    for (int t = lane; t < TLEN; t += 64)
        pout[t] = (float)path_sh[t];
}

extern "C" void kernel_launch(void* const* d_in, const int* in_sizes, int n_in,
                              void* d_out, int out_size, void* d_ws, size_t ws_size,
                              hipStream_t stream) {
    const float* feats = (const float*)d_in[0];
    const float* trans = (const float*)d_in[1];
    const int*   tags  = (const int*)d_in[2];
    float*       out   = (float*)d_out;
    (void)in_sizes; (void)n_in; (void)out_size;

    const size_t need = (size_t)BN * TLEN * KS;   // 25.2 MB backpointer scratch
    if (ws_size >= need) {
        crf_split<<<dim3(2 * BN), dim3(64), 0, stream>>>(feats, trans, tags, out,
                                                         (unsigned char*)d_ws);
    } else {
        crf_fused<<<dim3(BN), dim3(64), 0, stream>>>(feats, trans, tags, out);
    }
}

// Round 4
// 460.130 us; speedup vs baseline: 1.9692x; 1.3654x over previous
//
#include <hip/hip_runtime.h>
#include <math.h>

#define KS 48
#define TLEN 512
#define BN 1024
#define START_S 46
#define STOP_S 47
#define NEGV -10000.0f
#define PF 8   // emission prefetch depth

typedef float v2f __attribute__((ext_vector_type(2)));

__device__ __forceinline__ float bcast_lane0(float v) {
    return __builtin_bit_cast(float, __builtin_amdgcn_readfirstlane(__builtin_bit_cast(int, v)));
}

// grid = 2048: block b < 1024 -> forward (nll) for seq b
//              block b >= 1024 -> viterbi (path_score + path) for seq b-1024
// (1024 % 8 == 0 -> seq i's fwd and vit blocks land on the same XCD for L2 reuse)
__global__ __launch_bounds__(64) void crf_split(
    const float* __restrict__ feats,   // [B, T, K]
    const float* __restrict__ trans,   // [K, K]  trans[next, prev]
    const int*   __restrict__ tags,    // [B, T]
    float*       __restrict__ out,     // [B] nll | [B] path_score | [B*T] paths
    unsigned char* __restrict__ bp_g)  // [B, T, K] backpointers
{
    const int lane = threadIdx.x;
    const bool act = lane < KS;

    __shared__ float buf[2][64];
    __shared__ unsigned char path_sh[TLEN];
    __shared__ __align__(16) unsigned char seg[64 * KS];   // backtrace staging (3 KB)

    if (blockIdx.x < BN) {
        // ================= FORWARD =================
        const int b = blockIdx.x;
        const float* fb = feats + (size_t)b * TLEN * KS;
        const int*   tb = tags + (size_t)b * TLEN;

        float Erow[KS];   // exp(masked trans[next=lane][p]); exp(-10000)==0 masks for free
        {
            const float* tr = trans + (act ? lane : 0) * KS;
            #pragma unroll
            for (int p = 0; p < KS; ++p) {
                float tv = act ? tr[p] : NEGV;
                if (lane == START_S) tv = NEGV;
                if (p == STOP_S)     tv = NEGV;
                Erow[p] = __expf(tv);
            }
        }
        float tstart = act ? trans[lane * KS + START_S] : NEGV;
        if (lane == START_S) tstart = NEGV;

        // t=0 peeled: only prev=START contributes (others exp(-1e4)==0 exactly)
        float alpha = (act ? fb[lane] : -INFINITY) + tstart;

        auto fstep = [&](float emv, int t) {
            float s  = bcast_lane0(alpha);           // lane-0 alpha: finite, valid LSE shift
            float ue = __expf(alpha - s);            // -inf lanes -> 0
            const int bsel = t & 1;
            buf[bsel][lane] = ue;
            __syncthreads();                         // 1-wave block: waitcnt only
            const float4* uu = (const float4*)buf[bsel];
            v2f acc0 = {0.f, 0.f}, acc1 = {0.f, 0.f};
            #pragma unroll
            for (int g = 0; g < KS / 4; ++g) {
                float4 u = uu[g];
                v2f ua = {u.x, u.y}, ub = {u.z, u.w};
                v2f ea = {Erow[4 * g + 0], Erow[4 * g + 1]};
                v2f eb = {Erow[4 * g + 2], Erow[4 * g + 3]};
                acc0 = __builtin_elementwise_fma(ua, ea, acc0);
                acc1 = __builtin_elementwise_fma(ub, eb, acc1);
            }
            alpha = emv + s + __logf((acc0.x + acc0.y) + (acc1.x + acc1.y));
        };

        // steps t=1..511, 8-deep emission prefetch; 511 = 63*8 + 7
        float em[PF];
        #pragma unroll
        for (int j = 0; j < PF; ++j)
            em[j] = act ? fb[(1 + j) * KS + lane] : -INFINITY;
        for (int c = 0; c < 63; ++c) {
            const int t0 = 1 + c * PF;
            float em_n[PF];
            #pragma unroll
            for (int j = 0; j < PF; ++j) {
                int tf = t0 + PF + j;
                em_n[j] = (act && tf < TLEN) ? fb[tf * KS + lane] : -INFINITY;
            }
            #pragma unroll
            for (int j = 0; j < PF; ++j) fstep(em[j], t0 + j);
            #pragma unroll
            for (int j = 0; j < PF; ++j) em[j] = em_n[j];
        }
        #pragma unroll
        for (int j = 0; j < 7; ++j) fstep(em[j], 505 + j);

        float tstop = act ? trans[STOP_S * KS + lane] : NEGV;
        if (lane == STOP_S) tstop = NEGV;
        float z = alpha + tstop;
        float mz = z;
        #pragma unroll
        for (int off = 32; off; off >>= 1)
            mz = fmaxf(mz, __shfl_xor(mz, off, 64));
        float se = __expf(z - mz);
        #pragma unroll
        for (int off = 32; off; off >>= 1)
            se += __shfl_xor(se, off, 64);
        float logZ = mz + __logf(se);

        float g = 0.0f;
        for (int t = lane; t < TLEN; t += 64) {
            int tg = tb[t];
            int pg = (t == 0) ? START_S : tb[t - 1];
            g += fb[t * KS + tg] + trans[tg * KS + pg];
        }
        #pragma unroll
        for (int off = 32; off; off >>= 1)
            g += __shfl_xor(g, off, 64);
        g += trans[STOP_S * KS + tb[TLEN - 1]];

        if (lane == 0) out[b] = logZ - g;
    } else {
        // ================= VITERBI =================
        const int b = blockIdx.x - BN;
        const float* fb = feats + (size_t)b * TLEN * KS;
        unsigned char* bpb = bp_g + (size_t)b * TLEN * KS;

        float Trow[KS];   // masked trans[next=lane][p] — reference's exact add
        {
            const float* tr = trans + (act ? lane : 0) * KS;
            #pragma unroll
            for (int p = 0; p < KS; ++p) {
                float tv = act ? tr[p] : NEGV;
                if (lane == START_S) tv = NEGV;
                if (p == STOP_S)     tv = NEGV;
                Trow[p] = tv;
            }
        }

        float vit = (lane == START_S) ? 0.0f : NEGV;

        auto vstep = [&](float emv, int t) {
            const int bsel = t & 1;
            buf[bsel][lane] = vit;
            __syncthreads();
            const float4* ww = (const float4*)buf[bsel];
            // tree argmax (bit-exact max; ties impossible w.p.1 -> order immaterial)
            float bs[12]; int ib[12];
            #pragma unroll
            for (int g = 0; g < KS / 4; ++g) {
                float4 w = ww[g];
                v2f wa = {w.x, w.y}, wb = {w.z, w.w};
                v2f ta = {Trow[4 * g + 0], Trow[4 * g + 1]};
                v2f tc = {Trow[4 * g + 2], Trow[4 * g + 3]};
                v2f sa = wa + ta;                    // v_pk_add_f32
                v2f sb = wb + tc;
                float m01 = fmaxf(sa.x, sa.y); int i01 = (sa.y > sa.x) ? 4 * g + 1 : 4 * g + 0;
                float m23 = fmaxf(sb.x, sb.y); int i23 = (sb.y > sb.x) ? 4 * g + 3 : 4 * g + 2;
                bs[g] = fmaxf(m01, m23);       ib[g] = (m23 > m01) ? i23 : i01;
            }
            #pragma unroll
            for (int st = 0; st < 6; ++st) {
                float a = bs[2 * st], c2 = bs[2 * st + 1];
                int ia = ib[2 * st], ic = ib[2 * st + 1];
                bs[st] = fmaxf(a, c2); ib[st] = (c2 > a) ? ic : ia;
            }
            #pragma unroll
            for (int st = 0; st < 3; ++st) {
                float a = bs[2 * st], c2 = bs[2 * st + 1];
                int ia = ib[2 * st], ic = ib[2 * st + 1];
                bs[st] = fmaxf(a, c2); ib[st] = (c2 > a) ? ic : ia;
            }
            float best = fmaxf(bs[0], bs[1]);
            int   bi   = (bs[1] > bs[0]) ? ib[1] : ib[0];
            bi   = (bs[2] > best) ? ib[2] : bi;
            best = fmaxf(best, bs[2]);
            if (act) bpb[t * KS + lane] = (unsigned char)bi;   // fire-and-forget
            vit = best + emv;
        };

        // steps t=0..511, 8-deep prefetch; 512 = 64*8 exactly (no guards)
        float em[PF];
        #pragma unroll
        for (int j = 0; j < PF; ++j)
            em[j] = act ? fb[j * KS + lane] : 0.0f;
        for (int c = 0; c < 64; ++c) {
            const int t0 = c * PF;
            float em_n[PF];
            if (c < 63) {
                #pragma unroll
                for (int j = 0; j < PF; ++j)
                    em_n[j] = act ? fb[(t0 + PF + j) * KS + lane] : 0.0f;
            }
            #pragma unroll
            for (int j = 0; j < PF; ++j) vstep(em[j], t0 + j);
            if (c < 63) {
                #pragma unroll
                for (int j = 0; j < PF; ++j) em[j] = em_n[j];
            }
        }

        float tstop = act ? trans[STOP_S * KS + lane] : NEGV;
        if (lane == STOP_S) tstop = NEGV;
        float term = act ? (vit + tstop) : -3.0e38f;
        float bv = term;
        int   bidx = act ? lane : 9999;
        #pragma unroll
        for (int off = 32; off; off >>= 1) {
            float ov = __shfl_xor(bv, off, 64);
            int   oi = __shfl_xor(bidx, off, 64);
            if (ov > bv || (ov == bv && oi < bidx)) { bv = ov; bidx = oi; }
        }
        if (lane == 0) out[BN + b] = bv;

        // backtrace: 64-step segments staged into LDS (coalesced loads, LDS-latency walk)
        int tag = bidx;
        for (int s = 7; s >= 0; --s) {
            const float4* src = (const float4*)(bpb + s * 64 * KS);  // 3072 B, 16B-aligned
            float4* dst = (float4*)seg;
            #pragma unroll
            for (int i = 0; i < 3; ++i)
                dst[lane + 64 * i] = src[lane + 64 * i];
            __syncthreads();                                         // 1-wave: waitcnt
            for (int t = 63; t >= 0; --t) {
                path_sh[s * 64 + t] = (unsigned char)tag;            // uniform value
                tag = seg[t * KS + tag];
            }
            __syncthreads();                                         // WAR before next seg
        }
        float* pout = out + 2 * BN + (size_t)b * TLEN;
        for (int t = lane; t < TLEN; t += 64)
            pout[t] = (float)path_sh[t];
    }
}

// ============ fallback (ws too small): round-1 fused kernel, proven ============
__global__ __launch_bounds__(64) void crf_fused(
    const float* __restrict__ feats, const float* __restrict__ trans,
    const int* __restrict__ tags, float* __restrict__ out)
{
    const int b    = blockIdx.x;
    const int lane = threadIdx.x;
    const bool act = lane < KS;

    __shared__ float4 u4[KS / 4];
    __shared__ float4 w4[KS / 4];
    __shared__ unsigned char bp_sh[TLEN][KS];
    __shared__ unsigned char path_sh[TLEN];
    float* u_sh = (float*)u4;
    float* w_sh = (float*)w4;

    const float* fb = feats + (size_t)b * TLEN * KS;
    const int*   tb = tags + (size_t)b * TLEN;

    float Trow[KS], Erow[KS];
    {
        const float* tr = trans + (act ? lane : 0) * KS;
        #pragma unroll
        for (int p = 0; p < KS; ++p) {
            float tv = act ? tr[p] : NEGV;
            if (lane == START_S) tv = NEGV;
            if (p == STOP_S)     tv = NEGV;
            Trow[p] = tv;
            Erow[p] = __expf(tv);
        }
    }

    float alpha = (act && lane == START_S) ? 0.0f : -INFINITY;
    float vit   = (lane == START_S) ? 0.0f : (act ? NEGV : -3.0e38f);

    for (int t = 0; t < TLEN; ++t) {
        float emit = act ? fb[t * KS + lane] : 0.0f;
        float m = alpha;
        #pragma unroll
        for (int off = 32; off; off >>= 1)
            m = fmaxf(m, __shfl_xor(m, off, 64));
        float ue = __expf(alpha - m);
        if (act) { u_sh[lane] = ue; w_sh[lane] = vit; }
        __syncthreads();
        float acc = 0.0f, best = -3.0e38f; int bp = 0;
        #pragma unroll
        for (int p = 0; p < KS; p += 4) {
            float4 uu = u4[p / 4];
            float4 vv = w4[p / 4];
            acc = fmaf(uu.x, Erow[p + 0], acc);
            acc = fmaf(uu.y, Erow[p + 1], acc);
            acc = fmaf(uu.z, Erow[p + 2], acc);
            acc = fmaf(uu.w, Erow[p + 3], acc);
            float s0 = vv.x + Trow[p + 0]; if (s0 > best) { best = s0; bp = p + 0; }
            float s1 = vv.y + Trow[p + 1]; if (s1 > best) { best = s1; bp = p + 1; }
            float s2 = vv.z + Trow[p + 2]; if (s2 > best) { best = s2; bp = p + 2; }
            float s3 = vv.w + Trow[p + 3]; if (s3 > best) { best = s3; bp = p + 3; }
        }
        __syncthreads();
        alpha = emit + m + __logf(acc);
        vit   = best + emit;
        if (act) bp_sh[t][lane] = (unsigned char)bp;
    }

    float tstop = act ? trans[STOP_S * KS + lane] : NEGV;
    if (lane == STOP_S) tstop = NEGV;
    float z = alpha + tstop;
    float mz = z;
    #pragma unroll
    for (int off = 32; off; off >>= 1)
        mz = fmaxf(mz, __shfl_xor(mz, off, 64));
    float se = __expf(z - mz);
    #pragma unroll
    for (int off = 32; off; off >>= 1)
        se += __shfl_xor(se, off, 64);
    float logZ = mz + __logf(se);

    float term = act ? (vit + tstop) : -3.0e38f;
    float bv = term;
    int   bi = act ? lane : 9999;
    #pragma unroll
    for (int off = 32; off; off >>= 1) {
        float ov = __shfl_xor(bv, off, 64);
        int   oi = __shfl_xor(bi, off, 64);
        if (ov > bv || (ov == bv && oi < bi)) { bv = ov; bi = oi; }
    }

    float g = 0.0f;
    for (int t = lane; t < TLEN; t += 64) {
        int tg = tb[t];
        int pg = (t == 0) ? START_S : tb[t - 1];
        g += fb[t * KS + tg] + trans[tg * KS + pg];
    }
    #pragma unroll
    for (int off = 32; off; off >>= 1)
        g += __shfl_xor(g, off, 64);
    g += trans[STOP_S * KS + tb[TLEN - 1]];

    if (lane == 0) { out[b] = logZ - g; out[BN + b] = bv; }

    int tag = bi;
    for (int t = TLEN - 1; t >= 0; --t) {
        if (lane == 0) path_sh[t] = (unsigned char)tag;
        tag = bp_sh[t][tag];
    }
    __syncthreads();
    float* pout = out + 2 * BN + (size_t)b * TLEN;
    for (int t = lane; t < TLEN; t += 64)
        pout[t] = (float)path_sh[t];
}

extern "C" void kernel_launch(void* const* d_in, const int* in_sizes, int n_in,
                              void* d_out, int out_size, void* d_ws, size_t ws_size,
                              hipStream_t stream) {
    const float* feats = (const float*)d_in[0];
    const float* trans = (const float*)d_in[1];
    const int*   tags  = (const int*)d_in[2];
    float*       out   = (float*)d_out;
    (void)in_sizes; (void)n_in; (void)out_size;

    const size_t need = (size_t)BN * TLEN * KS;   // 25.2 MB backpointer scratch
    if (ws_size >= need) {
        crf_split<<<dim3(2 * BN), dim3(64), 0, stream>>>(feats, trans, tags, out,
                                                         (unsigned char*)d_ws);
    } else {
        crf_fused<<<dim3(BN), dim3(64), 0, stream>>>(feats, trans, tags, out);
    }
}